// Round 15
// baseline (127.615 us; speedup 1.0000x reference)
//
#include <hip/hip_runtime.h>

#define D_MODEL   256
#define NUM_TYPES 7
#define BATCH     2
#define NLANES    512
#define LSTR      264   // f16 LDS row stride: 528B/row
#define NBLOCKS   512u

typedef _Float16  f16x8   __attribute__((ext_vector_type(8)));
typedef float     floatx4 __attribute__((ext_vector_type(4)));

// ws: Hi16 @ 0 (512 KB) = f16(x@W1a+b1); Hj16 @ 512 KB (512 KB) = f16(x@W1b);
//     w2f @ 1 MB (8 KB) = W2^T MFMA A-fragments; barrier ctr @ 1 MB + 8 KB.
//
// ONE ordinary launch, 512 blocks x 256 thr (2 blocks/CU -> all co-resident by
// construction: LDS 33KBx2=66KB<160, 8 waves/CU). Hand-rolled grid barrier
// (HIP grid.sync pattern: threadfence; syncthreads; tid0 atomic arrive + spin;
// syncthreads). Counter zeroed per call via hipMemsetAsync (capture-legal).
//   Phase 1: r10-k1 verbatim (bid -> nt, r0) -> H halves + w2f table to ws.
//   Phase 2: r12 max-ILP pair body; 2 j-tiles per block sharing one Hi staging.
__global__ __launch_bounds__(256, 2) void k_fused(
    const float* __restrict__ x, const float* __restrict__ W1,
    const float* __restrict__ b1, const float* __restrict__ W2,
    const float* __restrict__ b2, _Float16* __restrict__ Hi16,
    _Float16* __restrict__ Hj16, _Float16* __restrict__ w2f,
    unsigned* __restrict__ ctr, float* __restrict__ out)
{
    __shared__ __align__(16) _Float16 smem[64 * LSTR];   // 33 KB

    const int tid  = threadIdx.x, lane = tid & 63, w = tid >> 6;
    const int bid  = blockIdx.x;                 // 0..511
    const int jr   = lane & 15, g = lane >> 4, ks = g * 8;

    // ================= PHASE 1: H16 = f16(x @ [W1a|W1b] (+b1)) =================
    {
        _Float16 (*xs)[LSTR] = (_Float16 (*)[LSTR])smem;
        const int nt   = bid & 31;               // 0..31 ; half = nt>>4
        const int half = nt >> 4;
        const int nc   = (nt & 15) * 16;
        const int r0   = (bid >> 5) * 64;        // row-tile base (0..960)

        // stage 64 x-rows (64 KB f32 -> 32 KB f16), fully coalesced
        {
            const float4* xsrc = (const float4*)(x + (size_t)r0 * D_MODEL);
            #pragma unroll
            for (int q = 0; q < 8; ++q) {
                const int gg = q * 512 + tid * 2;
                const int r  = gg >> 6;
                const int c4 = gg & 63;
                const float4 v0 = xsrc[gg];
                const float4 v1 = xsrc[gg + 1];
                f16x8 o;
                o[0] = (_Float16)v0.x; o[1] = (_Float16)v0.y;
                o[2] = (_Float16)v0.z; o[3] = (_Float16)v0.w;
                o[4] = (_Float16)v1.x; o[5] = (_Float16)v1.y;
                o[6] = (_Float16)v1.z; o[7] = (_Float16)v1.w;
                *(f16x8*)&xs[r][c4 * 4] = o;
            }
        }

        // B-frags: W1 cols nc..nc+15, strided (L2-hot); hides under staging
        f16x8 w1f[8];
        {
            const float* wb = W1 + (size_t)(half * D_MODEL + ks) * D_MODEL + nc + jr;
            #pragma unroll
            for (int kc = 0; kc < 8; ++kc)
                #pragma unroll
                for (int e = 0; e < 8; ++e)
                    w1f[kc][e] = (_Float16)wb[(size_t)(kc * 32 + e) * D_MODEL];
        }

        __syncthreads();

        floatx4 acc = {0.f, 0.f, 0.f, 0.f};
        #pragma unroll
        for (int kc = 0; kc < 8; ++kc) {
            const f16x8 a = *(const f16x8*)&xs[w * 16 + jr][kc * 32 + ks];
            acc = __builtin_amdgcn_mfma_f32_16x16x32_f16(a, w1f[kc], acc, 0, 0, 0);
        }

        _Float16* Hb = half ? Hj16 : Hi16;
        const float bias = half ? 0.f : b1[nc + jr];
        const int m0 = r0 + w * 16;
        #pragma unroll
        for (int r = 0; r < 4; ++r)
            Hb[(size_t)(m0 + g * 4 + r) * D_MODEL + nc + jr] = (_Float16)(acc[r] + bias);

        // block 0 builds the W2^T fragment table (8 KB)
        if (bid == 0) {
            #pragma unroll
            for (int s0 = 0; s0 < 2; ++s0) {
                const int s   = tid + s0 * 256;
                const int l2  = s & 63, kc2 = s >> 6;
                const int t2  = l2 & 15, ks2 = (l2 >> 4) * 8;
                f16x8 frag;
                #pragma unroll
                for (int e = 0; e < 8; ++e) {
                    const int k = kc2 * 32 + ks2 + e;
                    frag[e] = (t2 < NUM_TYPES)
                        ? (_Float16)W2[(size_t)k * NUM_TYPES + t2] : (_Float16)0.f;
                }
                *(f16x8*)(w2f + (size_t)s * 8) = frag;
            }
        }
    }

    // ================= hand-rolled grid barrier =================
    __threadfence();                 // make this block's H writes device-visible
    __syncthreads();
    if (tid == 0) {
        __hip_atomic_fetch_add(ctr, 1u, __ATOMIC_ACQ_REL, __HIP_MEMORY_SCOPE_AGENT);
        while (__hip_atomic_load(ctr, __ATOMIC_ACQUIRE, __HIP_MEMORY_SCOPE_AGENT)
               < NBLOCKS)
            __builtin_amdgcn_s_sleep(1);
    }
    __syncthreads();                 // all threads see acquire'd state

    // ================= PHASE 2: two pair-tiles (shared i0) =================
    {
        _Float16 (*hs)[LSTR] = (_Float16 (*)[LSTR])smem;  // rows 0..15 Hi, 16..47 Hj
        const int b   = bid >> 8;                 // batch
        const int rem = bid & 255;
        const int i0  = (rem >> 3) * 16;          // 32 i-tiles
        const int jc  = rem & 7;                  // j-chunk: tiles jc*2, jc*2+1

        // W2^T A-frags (resident across both tiles) + bias
        const f16x8* w2fp = (const f16x8*)w2f + lane;
        f16x8 w2r[8];
        #pragma unroll
        for (int kc = 0; kc < 8; ++kc)
            w2r[kc] = w2fp[kc * 64];

        const int tb = g * 4;
        float bias2[4];
        #pragma unroll
        for (int r = 0; r < 4; ++r)
            bias2[r] = (tb + r < NUM_TYPES) ? b2[tb + r] : 0.f;

        // stage Hi rows once (8 KB)
        #pragma unroll
        for (int q = 0; q < 2; ++q) {
            const int gg = tid + q * 256;
            const int r  = gg >> 5;
            const int c  = (gg & 31) * 8;
            *(f16x8*)&hs[r][c] = *(const f16x8*)(
                Hi16 + (size_t)(b * NLANES + i0 + r) * D_MODEL + c);
        }

        const int ig = w;                         // wave's 4 i's: i0 + ig*4 + u

        #pragma unroll 1
        for (int tt = 0; tt < 2; ++tt) {
            const int j0 = (jc * 2 + tt) * 32;

            // stage Hj rows 16..47 (16 KB) for this tile
            #pragma unroll
            for (int q = 0; q < 4; ++q) {
                const int gg = tid + q * 256;
                const int r  = gg >> 5;
                const int c  = (gg & 31) * 8;
                *(f16x8*)&hs[16 + r][c] = *(const f16x8*)(
                    Hj16 + (size_t)(b * NLANES + j0 + r) * D_MODEL + c);
            }
            __syncthreads();

            floatx4 acc[4][2];
            #pragma unroll
            for (int u = 0; u < 4; ++u)
                #pragma unroll
                for (int jg = 0; jg < 2; ++jg)
                    acc[u][jg] = (floatx4){0.f, 0.f, 0.f, 0.f};

            #pragma unroll
            for (int kch = 0; kch < 2; ++kch) {
                const int kb = kch * 128;

                f16x8 hj[2][4];                   // 8 ds_read_b128
                #pragma unroll
                for (int jg = 0; jg < 2; ++jg)
                    #pragma unroll
                    for (int kc = 0; kc < 4; ++kc)
                        hj[jg][kc] = *(const f16x8*)&hs[16 + jg * 16 + jr][kb + kc * 32 + ks];

                f16x8 hi[4][4];                   // 16 ds_read_b128 (broadcast)
                #pragma unroll
                for (int u = 0; u < 4; ++u)
                    #pragma unroll
                    for (int kc = 0; kc < 4; ++kc)
                        hi[u][kc] = *(const f16x8*)&hs[ig * 4 + u][kb + kc * 32 + ks];

                #pragma unroll
                for (int u = 0; u < 4; ++u)
                    #pragma unroll
                    for (int kc = 0; kc < 4; ++kc) {
                        const f16x8 z = {};
                        f16x8 s0 = __builtin_elementwise_max(hi[u][kc] + hj[0][kc], z);
                        acc[u][0] = __builtin_amdgcn_mfma_f32_16x16x32_f16(
                            w2r[kch * 4 + kc], s0, acc[u][0], 0, 0, 0);
                        f16x8 s1 = __builtin_elementwise_max(hi[u][kc] + hj[1][kc], z);
                        acc[u][1] = __builtin_amdgcn_mfma_f32_16x16x32_f16(
                            w2r[kch * 4 + kc], s1, acc[u][1], 0, 0, 0);
                    }
            }

            // store: lane<32 holds D[tb..tb+3][jr] (proven exact-WRITE pattern)
            if (lane < 32) {
                #pragma unroll
                for (int u = 0; u < 4; ++u) {
                    const int i = i0 + ig * 4 + u;
                    #pragma unroll
                    for (int jg = 0; jg < 2; ++jg) {
                        const floatx4 a = acc[u][jg];
                        const int j = j0 + jg * 16 + jr;
                        float* op = out + ((size_t)(b * NLANES + i) * NLANES + j) * NUM_TYPES + tb;
                        if (tb == 0) {
                            float v4[4] = { a[0] + bias2[0], a[1] + bias2[1],
                                            a[2] + bias2[2], a[3] + bias2[3] };
                            __builtin_memcpy(op, v4, 16);
                        } else {
                            float v2[2] = { a[0] + bias2[0], a[1] + bias2[1] };
                            __builtin_memcpy(op, v2, 8);
                            op[2] = a[2] + bias2[2];
                        }
                    }
                }
            }
            __syncthreads();   // hs safe to restage for tile 2
        }
    }
}

extern "C" void kernel_launch(void* const* d_in, const int* in_sizes, int n_in,
                              void* d_out, int out_size, void* d_ws, size_t ws_size,
                              hipStream_t stream) {
    const float* x  = (const float*)d_in[0];   // (2,512,256)
    const float* W1 = (const float*)d_in[1];   // (512,256)
    const float* b1 = (const float*)d_in[2];   // (256)
    const float* W2 = (const float*)d_in[3];   // (256,7)
    const float* b2 = (const float*)d_in[4];   // (7)
    float* out = (float*)d_out;                // (2,512,512,7) fp32

    char* ws = (char*)d_ws;
    _Float16* Hi16 = (_Float16*)ws;
    _Float16* Hj16 = (_Float16*)(ws + 512u * 1024u);
    _Float16* w2f  = (_Float16*)(ws + 1024u * 1024u);
    unsigned* ctr  = (unsigned*)(ws + 1024u * 1024u + 8u * 1024u);

    hipMemsetAsync(ctr, 0, sizeof(unsigned), stream);   // capture-legal async op
    k_fused<<<dim3(NBLOCKS), 256, 0, stream>>>(
        x, W1, b1, W2, b2, Hi16, Hj16, w2f, ctr, out);
}

// Round 16
// 51.700 us; speedup vs baseline: 2.4684x; 2.4684x over previous
//
#include <hip/hip_runtime.h>

#define D_MODEL   256
#define NUM_TYPES 7
#define BATCH     2
#define NLANES    512
#define LSTR      264   // f16 LDS row stride: 528B/row
#define K2_REPS   5     // instrumentation dilation (identical work+output per rep)

typedef _Float16  f16x8   __attribute__((ext_vector_type(8)));
typedef float     floatx4 __attribute__((ext_vector_type(4)));

// ws: Hi16 @ 0 (512 KB) = f16(x@W1a+b1); Hj16 @ 512 KB (512 KB) = f16(x@W1b);
//     w2f @ 1 MB (8 KB) = W2^T MFMA A-fragments (slot = kc*64+lane, f16x8 each).

// ---------------- Kernel 1: H16 = f16(x @ [W1a|W1b] (+b1)) via f16 MFMA ----------
// (r10-proven: x-tile staged coalesced into LDS as f16; ~2.5 us)
__global__ __launch_bounds__(256) void k1_mfma(
    const float* __restrict__ x, const float* __restrict__ W1,
    const float* __restrict__ b1, const float* __restrict__ W2,
    _Float16* __restrict__ Hi16, _Float16* __restrict__ Hj16,
    _Float16* __restrict__ w2f)
{
    __shared__ __align__(16) _Float16 xs[64][LSTR];   // 33 KB

    const int tid  = threadIdx.x, lane = tid & 63, w = tid >> 6;
    const int nt   = blockIdx.x;                  // 0..31 ; half = nt>>4
    const int half = nt >> 4;
    const int nc   = (nt & 15) * 16;
    const int r0   = blockIdx.y * 64;             // row-tile base
    const int jr   = lane & 15, g = lane >> 4, ks = g * 8;

    // ---- stage 64 x-rows (64 KB f32 -> 32 KB f16), fully coalesced ----
    {
        const float4* xsrc = (const float4*)(x + (size_t)r0 * D_MODEL);
        #pragma unroll
        for (int q = 0; q < 8; ++q) {
            const int gg = q * 512 + tid * 2;     // float4 granule (pair start)
            const int r  = gg >> 6;               // row 0..63
            const int c4 = gg & 63;               // even
            const float4 v0 = xsrc[gg];
            const float4 v1 = xsrc[gg + 1];
            f16x8 o;
            o[0] = (_Float16)v0.x; o[1] = (_Float16)v0.y;
            o[2] = (_Float16)v0.z; o[3] = (_Float16)v0.w;
            o[4] = (_Float16)v1.x; o[5] = (_Float16)v1.y;
            o[6] = (_Float16)v1.z; o[7] = (_Float16)v1.w;
            *(f16x8*)&xs[r][c4 * 4] = o;
        }
    }

    // ---- B-frags: W1 cols nc..nc+15, strided (L2-hot); hides under staging ----
    f16x8 w1f[8];
    {
        const float* wb = W1 + (size_t)(half * D_MODEL + ks) * D_MODEL + nc + jr;
        #pragma unroll
        for (int kc = 0; kc < 8; ++kc)
            #pragma unroll
            for (int e = 0; e < 8; ++e)
                w1f[kc][e] = (_Float16)wb[(size_t)(kc * 32 + e) * D_MODEL];
    }

    __syncthreads();

    // ---- wave w: rows r0 + w*16 .. +15 ----
    floatx4 acc = {0.f, 0.f, 0.f, 0.f};
    #pragma unroll
    for (int kc = 0; kc < 8; ++kc) {
        const f16x8 a = *(const f16x8*)&xs[w * 16 + jr][kc * 32 + ks];
        acc = __builtin_amdgcn_mfma_f32_16x16x32_f16(a, w1f[kc], acc, 0, 0, 0);
    }

    _Float16* Hb = half ? Hj16 : Hi16;
    const float bias = half ? 0.f : b1[nc + jr];
    const int m0 = r0 + w * 16;
    #pragma unroll
    for (int r = 0; r < 4; ++r)
        Hb[(size_t)(m0 + g * 4 + r) * D_MODEL + nc + jr] = (_Float16)(acc[r] + bias);

    // ---- one block builds the W2^T fragment table (8 KB) ----
    if (nt == 0 && blockIdx.y == 0) {
        #pragma unroll
        for (int s0 = 0; s0 < 2; ++s0) {
            const int s   = tid + s0 * 256;       // slot 0..511
            const int l2  = s & 63, kc2 = s >> 6;
            const int t2  = l2 & 15, ks2 = (l2 >> 4) * 8;
            f16x8 frag;
            #pragma unroll
            for (int e = 0; e < 8; ++e) {
                const int k = kc2 * 32 + ks2 + e;
                frag[e] = (t2 < NUM_TYPES)
                    ? (_Float16)W2[(size_t)k * NUM_TYPES + t2] : (_Float16)0.f;
            }
            *(f16x8*)(w2f + (size_t)s * 8) = frag;
        }
    }
}

// ---------------- Kernel 2 (x5 DILATED for profiling visibility) ----------------
// r12 body, repeated K2_REPS times with opaque pointers (no CSE). Each rep does
// the full stage + compute + store identically -> per-rep behavior = real kernel.
__global__ __launch_bounds__(256, 3) void k2_pair(
    const _Float16* __restrict__ Hi16, const _Float16* __restrict__ Hj16,
    const _Float16* __restrict__ w2f, const float* __restrict__ b2,
    float* __restrict__ out)
{
    __shared__ _Float16 hs[48][LSTR];   // rows 0..15: Hi(i0+r); 16..47: Hj(j0+r-16)

    const int tid  = threadIdx.x;       // 0..255
    const int lane = tid & 63, w = tid >> 6;
    const int b    = blockIdx.z;
    const int j0   = blockIdx.x * 32;
    const int i0   = blockIdx.y * 16;
    const int jr   = lane & 15, g = lane >> 4, ks = g * 8;

    const int tb = g * 4;
    float bias2[4];
    #pragma unroll
    for (int r = 0; r < 4; ++r)
        bias2[r] = (tb + r < NUM_TYPES) ? b2[tb + r] : 0.f;

    const int ig = w;                   // wave's 4 i's: i0 + ig*4 + u

    #pragma unroll 1
    for (int rep = 0; rep < K2_REPS; ++rep) {
        // opaque copies: prevent cross-rep CSE/hoisting of loads
        const _Float16* HiP = Hi16;
        const _Float16* HjP = Hj16;
        const _Float16* WfP = w2f;
        asm volatile("" : "+r"(HiP), "+r"(HjP), "+r"(WfP));

        // ---- stage 48 rows (24 KB of H), uniform Hi / Hj halves, coalesced ----
        #pragma unroll
        for (int q = 0; q < 2; ++q) {   // granules 0..511 -> Hi rows 0..15
            const int gg = tid + q * 256;
            const int r  = gg >> 5;
            const int c  = (gg & 31) * 8;
            *(f16x8*)&hs[r][c] = *(const f16x8*)(
                HiP + (size_t)(b * NLANES + i0 + r) * D_MODEL + c);
        }
        #pragma unroll
        for (int q = 0; q < 4; ++q) {   // granules 0..1023 -> Hj rows 16..47
            const int gg = tid + q * 256;
            const int r  = gg >> 5;
            const int c  = (gg & 31) * 8;
            *(f16x8*)&hs[16 + r][c] = *(const f16x8*)(
                HjP + (size_t)(b * NLANES + j0 + r) * D_MODEL + c);
        }

        __syncthreads();

        const f16x8* w2fp = (const f16x8*)WfP + lane;   // + (kch*4+kc)*64

        floatx4 acc[4][2];
        #pragma unroll
        for (int u = 0; u < 4; ++u)
            #pragma unroll
            for (int jg = 0; jg < 2; ++jg)
                acc[u][jg] = (floatx4){0.f, 0.f, 0.f, 0.f};

        #pragma unroll
        for (int kch = 0; kch < 2; ++kch) {
            const int kb = kch * 128;   // f16 col base of this k-half

            f16x8 w2h[4];               // 4 global b128 (L1/L2-hot)
            #pragma unroll
            for (int kc = 0; kc < 4; ++kc)
                w2h[kc] = w2fp[(kch * 4 + kc) * 64];

            f16x8 hj[2][4];             // 8 ds_read_b128
            #pragma unroll
            for (int jg = 0; jg < 2; ++jg)
                #pragma unroll
                for (int kc = 0; kc < 4; ++kc)
                    hj[jg][kc] = *(const f16x8*)&hs[16 + jg * 16 + jr][kb + kc * 32 + ks];

            f16x8 hi[4][4];             // 16 ds_read_b128 (broadcast in 16-groups)
            #pragma unroll
            for (int u = 0; u < 4; ++u)
                #pragma unroll
                for (int kc = 0; kc < 4; ++kc)
                    hi[u][kc] = *(const f16x8*)&hs[ig * 4 + u][kb + kc * 32 + ks];

            #pragma unroll
            for (int u = 0; u < 4; ++u)
                #pragma unroll
                for (int kc = 0; kc < 4; ++kc) {
                    const f16x8 z = {};
                    f16x8 s0 = __builtin_elementwise_max(hi[u][kc] + hj[0][kc], z);
                    acc[u][0] = __builtin_amdgcn_mfma_f32_16x16x32_f16(
                        w2h[kc], s0, acc[u][0], 0, 0, 0);
                    f16x8 s1 = __builtin_elementwise_max(hi[u][kc] + hj[1][kc], z);
                    acc[u][1] = __builtin_amdgcn_mfma_f32_16x16x32_f16(
                        w2h[kc], s1, acc[u][1], 0, 0, 0);
                }
        }

        // ---- store: lane<32 holds D[tb..tb+3][jr] (proven exact-WRITE pattern) ----
        if (lane < 32) {
            #pragma unroll
            for (int u = 0; u < 4; ++u) {
                const int i = i0 + ig * 4 + u;
                #pragma unroll
                for (int jg = 0; jg < 2; ++jg) {
                    const floatx4 a = acc[u][jg];
                    const int j = j0 + jg * 16 + jr;
                    float* op = out + ((size_t)(b * NLANES + i) * NLANES + j) * NUM_TYPES + tb;
                    if (tb == 0) {
                        float v4[4] = { a[0] + bias2[0], a[1] + bias2[1],
                                        a[2] + bias2[2], a[3] + bias2[3] };
                        __builtin_memcpy(op, v4, 16);
                    } else {
                        float v2[2] = { a[0] + bias2[0], a[1] + bias2[1] };
                        __builtin_memcpy(op, v2, 8);
                        op[2] = a[2] + bias2[2];
                    }
                }
            }
        }
        __syncthreads();   // hs safe to restage next rep
    }
}

extern "C" void kernel_launch(void* const* d_in, const int* in_sizes, int n_in,
                              void* d_out, int out_size, void* d_ws, size_t ws_size,
                              hipStream_t stream) {
    const float* x  = (const float*)d_in[0];   // (2,512,256)
    const float* W1 = (const float*)d_in[1];   // (512,256)
    const float* b1 = (const float*)d_in[2];   // (256)
    const float* W2 = (const float*)d_in[3];   // (256,7)
    const float* b2 = (const float*)d_in[4];   // (7)
    float* out = (float*)d_out;                // (2,512,512,7) fp32

    char* ws = (char*)d_ws;
    _Float16* Hi16 = (_Float16*)ws;
    _Float16* Hj16 = (_Float16*)(ws + 512u * 1024u);
    _Float16* w2f  = (_Float16*)(ws + 1024u * 1024u);

    k1_mfma<<<dim3(32, 16), 256, 0, stream>>>(x, W1, b1, W2, Hi16, Hj16, w2f);
    k2_pair<<<dim3(NLANES / 32, NLANES / 16, BATCH), 256, 0, stream>>>(
        Hi16, Hj16, w2f, b2, out);
}

// Round 17
// 24.883 us; speedup vs baseline: 5.1285x; 2.0777x over previous
//
#include <hip/hip_runtime.h>

#define D_MODEL   256
#define NUM_TYPES 7
#define BATCH     2
#define NLANES    512
#define LSTR      264   // f16 LDS row stride: 528B/row

typedef _Float16  f16x8   __attribute__((ext_vector_type(8)));
typedef float     floatx4 __attribute__((ext_vector_type(4)));

// ws: Hi16 @ 0 (512 KB) = f16(x@W1a+b1); Hj16 @ 512 KB (512 KB) = f16(x@W1b);
//     w2f @ 1 MB (8 KB) = W2^T MFMA A-fragments (slot = kc*64+lane, f16x8 each).

// ---------------- Kernel 1: H16 = f16(x @ [W1a|W1b] (+b1)) via f16 MFMA ----------
// (r10-proven: x-tile staged coalesced into LDS as f16; ~2.5 us)
__global__ __launch_bounds__(256) void k1_mfma(
    const float* __restrict__ x, const float* __restrict__ W1,
    const float* __restrict__ b1, const float* __restrict__ W2,
    _Float16* __restrict__ Hi16, _Float16* __restrict__ Hj16,
    _Float16* __restrict__ w2f)
{
    __shared__ __align__(16) _Float16 xs[64][LSTR];   // 33 KB

    const int tid  = threadIdx.x, lane = tid & 63, w = tid >> 6;
    const int nt   = blockIdx.x;                  // 0..31 ; half = nt>>4
    const int half = nt >> 4;
    const int nc   = (nt & 15) * 16;
    const int r0   = blockIdx.y * 64;             // row-tile base
    const int jr   = lane & 15, g = lane >> 4, ks = g * 8;

    // ---- stage 64 x-rows (64 KB f32 -> 32 KB f16), fully coalesced ----
    {
        const float4* xsrc = (const float4*)(x + (size_t)r0 * D_MODEL);
        #pragma unroll
        for (int q = 0; q < 8; ++q) {
            const int gg = q * 512 + tid * 2;     // float4 granule (pair start)
            const int r  = gg >> 6;               // row 0..63
            const int c4 = gg & 63;               // even
            const float4 v0 = xsrc[gg];
            const float4 v1 = xsrc[gg + 1];
            f16x8 o;
            o[0] = (_Float16)v0.x; o[1] = (_Float16)v0.y;
            o[2] = (_Float16)v0.z; o[3] = (_Float16)v0.w;
            o[4] = (_Float16)v1.x; o[5] = (_Float16)v1.y;
            o[6] = (_Float16)v1.z; o[7] = (_Float16)v1.w;
            *(f16x8*)&xs[r][c4 * 4] = o;
        }
    }

    // ---- B-frags: W1 cols nc..nc+15, strided (L2-hot); hides under staging ----
    f16x8 w1f[8];
    {
        const float* wb = W1 + (size_t)(half * D_MODEL + ks) * D_MODEL + nc + jr;
        #pragma unroll
        for (int kc = 0; kc < 8; ++kc)
            #pragma unroll
            for (int e = 0; e < 8; ++e)
                w1f[kc][e] = (_Float16)wb[(size_t)(kc * 32 + e) * D_MODEL];
    }

    __syncthreads();

    // ---- wave w: rows r0 + w*16 .. +15 ----
    floatx4 acc = {0.f, 0.f, 0.f, 0.f};
    #pragma unroll
    for (int kc = 0; kc < 8; ++kc) {
        const f16x8 a = *(const f16x8*)&xs[w * 16 + jr][kc * 32 + ks];
        acc = __builtin_amdgcn_mfma_f32_16x16x32_f16(a, w1f[kc], acc, 0, 0, 0);
    }

    _Float16* Hb = half ? Hj16 : Hi16;
    const float bias = half ? 0.f : b1[nc + jr];
    const int m0 = r0 + w * 16;
    #pragma unroll
    for (int r = 0; r < 4; ++r)
        Hb[(size_t)(m0 + g * 4 + r) * D_MODEL + nc + jr] = (_Float16)(acc[r] + bias);

    // ---- one block builds the W2^T fragment table (8 KB) ----
    if (nt == 0 && blockIdx.y == 0) {
        #pragma unroll
        for (int s0 = 0; s0 < 2; ++s0) {
            const int s   = tid + s0 * 256;       // slot 0..511
            const int l2  = s & 63, kc2 = s >> 6;
            const int t2  = l2 & 15, ks2 = (l2 >> 4) * 8;
            f16x8 frag;
            #pragma unroll
            for (int e = 0; e < 8; ++e) {
                const int k = kc2 * 32 + ks2 + e;
                frag[e] = (t2 < NUM_TYPES)
                    ? (_Float16)W2[(size_t)k * NUM_TYPES + t2] : (_Float16)0.f;
            }
            *(f16x8*)(w2f + (size_t)s * 8) = frag;
        }
    }
}

// ---------------- Kernel 2: out[b,i,j,:] = relu(Hi[i]+Hj[j]) @ W2 + b2 ----------
// TWO j-tiles per block (grid 8x32x2 = 512 blocks), T14 async-STAGE split:
// Hi staged once; Hj tile-1 issued EARLY into regs (latency hides under tile-0
// compute), written LATE to LDS after tile-0's reads. r12 max-ILP compute body.
__global__ __launch_bounds__(256, 4) void k2_pair(
    const _Float16* __restrict__ Hi16, const _Float16* __restrict__ Hj16,
    const _Float16* __restrict__ w2f, const float* __restrict__ b2,
    float* __restrict__ out)
{
    __shared__ _Float16 hs[48][LSTR];   // rows 0..15: Hi(i0+r); 16..47: Hj tile

    const int tid  = threadIdx.x;       // 0..255
    const int lane = tid & 63, w = tid >> 6;
    const int b    = blockIdx.z;
    const int jc   = blockIdx.x;        // j-chunk: tiles at jc*64, jc*64+32
    const int i0   = blockIdx.y * 16;
    const int jr   = lane & 15, g = lane >> 4, ks = g * 8;

    const int sr = tid >> 5;            // staging row 0..7 step, col granule:
    const int sc = (tid & 31) * 8;      // (tid+q*256) -> row (gg>>5), col granule

    // ---- stage Hi rows 0..15 + Hj tile-0 rows 16..47, coalesced ----
    #pragma unroll
    for (int q = 0; q < 2; ++q) {
        const int r = sr + q * 8;
        *(f16x8*)&hs[r][sc] = *(const f16x8*)(
            Hi16 + (size_t)(b * NLANES + i0 + r) * D_MODEL + sc);
    }
    #pragma unroll
    for (int q = 0; q < 4; ++q) {
        const int r = sr + q * 8;
        *(f16x8*)&hs[16 + r][sc] = *(const f16x8*)(
            Hj16 + (size_t)(b * NLANES + jc * 64 + r) * D_MODEL + sc);
    }

    const int tb = g * 4;
    float bias2[4];
    #pragma unroll
    for (int r = 0; r < 4; ++r)
        bias2[r] = (tb + r < NUM_TYPES) ? b2[tb + r] : 0.f;

    __syncthreads();

    // ---- T14 issue-early: Hj tile-1 -> regs (hides under tile-0 compute) ----
    f16x8 pj[4];
    #pragma unroll
    for (int q = 0; q < 4; ++q) {
        const int r = sr + q * 8;
        pj[q] = *(const f16x8*)(
            Hj16 + (size_t)(b * NLANES + jc * 64 + 32 + r) * D_MODEL + sc);
    }

    const int ig = w;                   // wave's 4 i's: i0 + ig*4 + u
    const f16x8* w2fp = (const f16x8*)w2f + lane;   // + (kch*4+kc)*64

    #pragma unroll 1
    for (int tt = 0; tt < 2; ++tt) {
        const int j0 = jc * 64 + tt * 32;

        floatx4 acc[4][2];
        #pragma unroll
        for (int u = 0; u < 4; ++u)
            #pragma unroll
            for (int jg = 0; jg < 2; ++jg)
                acc[u][jg] = (floatx4){0.f, 0.f, 0.f, 0.f};

        #pragma unroll
        for (int kch = 0; kch < 2; ++kch) {
            const int kb = kch * 128;   // f16 col base of this k-half

            f16x8 w2h[4];               // 4 global b128 (L1/L2-hot)
            #pragma unroll
            for (int kc = 0; kc < 4; ++kc)
                w2h[kc] = w2fp[(kch * 4 + kc) * 64];

            f16x8 hj[2][4];             // 8 ds_read_b128
            #pragma unroll
            for (int jg = 0; jg < 2; ++jg)
                #pragma unroll
                for (int kc = 0; kc < 4; ++kc)
                    hj[jg][kc] = *(const f16x8*)&hs[16 + jg * 16 + jr][kb + kc * 32 + ks];

            f16x8 hi[4][4];             // 16 ds_read_b128 (broadcast in 16-groups)
            #pragma unroll
            for (int u = 0; u < 4; ++u)
                #pragma unroll
                for (int kc = 0; kc < 4; ++kc)
                    hi[u][kc] = *(const f16x8*)&hs[ig * 4 + u][kb + kc * 32 + ks];

            #pragma unroll
            for (int u = 0; u < 4; ++u)
                #pragma unroll
                for (int kc = 0; kc < 4; ++kc) {
                    const f16x8 z = {};
                    f16x8 s0 = __builtin_elementwise_max(hi[u][kc] + hj[0][kc], z);
                    acc[u][0] = __builtin_amdgcn_mfma_f32_16x16x32_f16(
                        w2h[kc], s0, acc[u][0], 0, 0, 0);
                    f16x8 s1 = __builtin_elementwise_max(hi[u][kc] + hj[1][kc], z);
                    acc[u][1] = __builtin_amdgcn_mfma_f32_16x16x32_f16(
                        w2h[kc], s1, acc[u][1], 0, 0, 0);
                }
        }

        // ---- store: lane<32 holds D[tb..tb+3][jr] (proven exact-WRITE pattern) ----
        if (lane < 32) {
            #pragma unroll
            for (int u = 0; u < 4; ++u) {
                const int i = i0 + ig * 4 + u;
                #pragma unroll
                for (int jg = 0; jg < 2; ++jg) {
                    const floatx4 a = acc[u][jg];
                    const int j = j0 + jg * 16 + jr;
                    float* op = out + ((size_t)(b * NLANES + i) * NLANES + j) * NUM_TYPES + tb;
                    if (tb == 0) {
                        float v4[4] = { a[0] + bias2[0], a[1] + bias2[1],
                                        a[2] + bias2[2], a[3] + bias2[3] };
                        __builtin_memcpy(op, v4, 16);
                    } else {
                        float v2[2] = { a[0] + bias2[0], a[1] + bias2[1] };
                        __builtin_memcpy(op, v2, 8);
                        op[2] = a[2] + bias2[2];
                    }
                }
            }
        }

        // ---- T14 write-late: commit Hj tile-1 to LDS between tiles ----
        if (tt == 0) {
            __syncthreads();            // tile-0 LDS reads complete
            #pragma unroll
            for (int q = 0; q < 4; ++q)
                *(f16x8*)&hs[16 + sr + q * 8][sc] = pj[q];
            __syncthreads();            // tile-1 data visible
        }
    }
}

extern "C" void kernel_launch(void* const* d_in, const int* in_sizes, int n_in,
                              void* d_out, int out_size, void* d_ws, size_t ws_size,
                              hipStream_t stream) {
    const float* x  = (const float*)d_in[0];   // (2,512,256)
    const float* W1 = (const float*)d_in[1];   // (512,256)
    const float* b1 = (const float*)d_in[2];   // (256)
    const float* W2 = (const float*)d_in[3];   // (256,7)
    const float* b2 = (const float*)d_in[4];   // (7)
    float* out = (float*)d_out;                // (2,512,512,7) fp32

    char* ws = (char*)d_ws;
    _Float16* Hi16 = (_Float16*)ws;
    _Float16* Hj16 = (_Float16*)(ws + 512u * 1024u);
    _Float16* w2f  = (_Float16*)(ws + 1024u * 1024u);

    k1_mfma<<<dim3(32, 16), 256, 0, stream>>>(x, W1, b1, W2, Hi16, Hj16, w2f);
    // grid: (j-chunks of 64, i-tiles of 16, batch) = (8, 32, 2) = 512 blocks
    k2_pair<<<dim3(8, 32, BATCH), 256, 0, stream>>>(Hi16, Hj16, w2f, b2, out);
}

// Round 18
// 20.363 us; speedup vs baseline: 6.2671x; 1.2220x over previous
//
#include <hip/hip_runtime.h>

#define D_MODEL   256
#define NUM_TYPES 7
#define BATCH     2
#define NLANES    512
#define LSTR      264   // f16 LDS row stride: 528B/row

typedef _Float16  f16x8   __attribute__((ext_vector_type(8)));
typedef float     floatx4 __attribute__((ext_vector_type(4)));

// ws: Hi16 @ 0 (512 KB) = f16(x@W1a+b1); Hj16 @ 512 KB (512 KB) = f16(x@W1b);
//     w2f @ 1 MB (8 KB) = W2^T MFMA A-fragments (slot = kc*64+lane, f16x8 each).

// ---------------- Kernel 1: H16 = f16(x @ [W1a|W1b] (+b1)) via f16 MFMA ----------
// (r10-proven: x-tile staged coalesced into LDS as f16; ~2.5 us)
__global__ __launch_bounds__(256) void k1_mfma(
    const float* __restrict__ x, const float* __restrict__ W1,
    const float* __restrict__ b1, const float* __restrict__ W2,
    _Float16* __restrict__ Hi16, _Float16* __restrict__ Hj16,
    _Float16* __restrict__ w2f)
{
    __shared__ __align__(16) _Float16 xs[64][LSTR];   // 33 KB

    const int tid  = threadIdx.x, lane = tid & 63, w = tid >> 6;
    const int nt   = blockIdx.x;                  // 0..31 ; half = nt>>4
    const int half = nt >> 4;
    const int nc   = (nt & 15) * 16;
    const int r0   = blockIdx.y * 64;             // row-tile base
    const int jr   = lane & 15, g = lane >> 4, ks = g * 8;

    // ---- stage 64 x-rows (64 KB f32 -> 32 KB f16), fully coalesced ----
    {
        const float4* xsrc = (const float4*)(x + (size_t)r0 * D_MODEL);
        #pragma unroll
        for (int q = 0; q < 8; ++q) {
            const int gg = q * 512 + tid * 2;     // float4 granule (pair start)
            const int r  = gg >> 6;               // row 0..63
            const int c4 = gg & 63;               // even
            const float4 v0 = xsrc[gg];
            const float4 v1 = xsrc[gg + 1];
            f16x8 o;
            o[0] = (_Float16)v0.x; o[1] = (_Float16)v0.y;
            o[2] = (_Float16)v0.z; o[3] = (_Float16)v0.w;
            o[4] = (_Float16)v1.x; o[5] = (_Float16)v1.y;
            o[6] = (_Float16)v1.z; o[7] = (_Float16)v1.w;
            *(f16x8*)&xs[r][c4 * 4] = o;
        }
    }

    // ---- B-frags: W1 cols nc..nc+15, strided (L2-hot); hides under staging ----
    f16x8 w1f[8];
    {
        const float* wb = W1 + (size_t)(half * D_MODEL + ks) * D_MODEL + nc + jr;
        #pragma unroll
        for (int kc = 0; kc < 8; ++kc)
            #pragma unroll
            for (int e = 0; e < 8; ++e)
                w1f[kc][e] = (_Float16)wb[(size_t)(kc * 32 + e) * D_MODEL];
    }

    __syncthreads();

    // ---- wave w: rows r0 + w*16 .. +15 ----
    floatx4 acc = {0.f, 0.f, 0.f, 0.f};
    #pragma unroll
    for (int kc = 0; kc < 8; ++kc) {
        const f16x8 a = *(const f16x8*)&xs[w * 16 + jr][kc * 32 + ks];
        acc = __builtin_amdgcn_mfma_f32_16x16x32_f16(a, w1f[kc], acc, 0, 0, 0);
    }

    _Float16* Hb = half ? Hj16 : Hi16;
    const float bias = half ? 0.f : b1[nc + jr];
    const int m0 = r0 + w * 16;
    #pragma unroll
    for (int r = 0; r < 4; ++r)
        Hb[(size_t)(m0 + g * 4 + r) * D_MODEL + nc + jr] = (_Float16)(acc[r] + bias);

    // ---- one block builds the W2^T fragment table (8 KB) ----
    if (nt == 0 && blockIdx.y == 0) {
        #pragma unroll
        for (int s0 = 0; s0 < 2; ++s0) {
            const int s   = tid + s0 * 256;       // slot 0..511
            const int l2  = s & 63, kc2 = s >> 6;
            const int t2  = l2 & 15, ks2 = (l2 >> 4) * 8;
            f16x8 frag;
            #pragma unroll
            for (int e = 0; e < 8; ++e) {
                const int k = kc2 * 32 + ks2 + e;
                frag[e] = (t2 < NUM_TYPES)
                    ? (_Float16)W2[(size_t)k * NUM_TYPES + t2] : (_Float16)0.f;
            }
            *(f16x8*)(w2f + (size_t)s * 8) = frag;
        }
    }
}

// ---------------- Kernel 2: out[b,i,j,:] = relu(Hi[i]+Hj[j]) @ W2 + b2 ----------
// Tile 16i x 16j, 256 thr = 4 waves, grid (32,32,2) = 2048 blocks (~8/CU by LDS).
// TLP-first: twice the co-resident blocks of r12 so stage/drain phases of one
// block hide under compute of others. Wave = 4 i's x 16 j. Max-ILP body.
__global__ __launch_bounds__(256, 4) void k2_pair(
    const _Float16* __restrict__ Hi16, const _Float16* __restrict__ Hj16,
    const _Float16* __restrict__ w2f, const float* __restrict__ b2,
    float* __restrict__ out)
{
    __shared__ _Float16 hs[32][LSTR];   // rows 0..15: Hi(i0+r); 16..31: Hj(j0+r-16)

    const int tid  = threadIdx.x;       // 0..255
    const int lane = tid & 63, w = tid >> 6;
    const int b    = blockIdx.z;
    const int j0   = blockIdx.x * 16;
    const int i0   = blockIdx.y * 16;
    const int jr   = lane & 15, g = lane >> 4, ks = g * 8;

    // ---- stage 32 rows (16 KB of H), coalesced f16x8 ----
    const int sr = tid >> 5;            // 0..7
    const int sc = (tid & 31) * 8;      // f16 col granule
    #pragma unroll
    for (int q = 0; q < 2; ++q) {
        const int r = sr + q * 8;
        *(f16x8*)&hs[r][sc] = *(const f16x8*)(
            Hi16 + (size_t)(b * NLANES + i0 + r) * D_MODEL + sc);
        *(f16x8*)&hs[16 + r][sc] = *(const f16x8*)(
            Hj16 + (size_t)(b * NLANES + j0 + r) * D_MODEL + sc);
    }

    const int tb = g * 4;
    float bias2[4];
    #pragma unroll
    for (int r = 0; r < 4; ++r)
        bias2[r] = (tb + r < NUM_TYPES) ? b2[tb + r] : 0.f;

    __syncthreads();

    const int ig = w;                   // wave's 4 i's: i0 + ig*4 + u
    const f16x8* w2fp = (const f16x8*)w2f + lane;   // + (kch*4+kc)*64

    floatx4 acc[4];
    #pragma unroll
    for (int u = 0; u < 4; ++u) acc[u] = (floatx4){0.f, 0.f, 0.f, 0.f};

    #pragma unroll
    for (int kch = 0; kch < 2; ++kch) {
        const int kb = kch * 128;       // f16 col base of this k-half

        // ---- all loads for this k-half issued together (max ILP) ----
        f16x8 w2h[4];                   // 4 global b128 (L1/L2-hot)
        #pragma unroll
        for (int kc = 0; kc < 4; ++kc)
            w2h[kc] = w2fp[(kch * 4 + kc) * 64];

        f16x8 hj[4];                    // 4 ds_read_b128
        #pragma unroll
        for (int kc = 0; kc < 4; ++kc)
            hj[kc] = *(const f16x8*)&hs[16 + jr][kb + kc * 32 + ks];

        f16x8 hi[4][4];                 // 16 ds_read_b128 (broadcast in 16-groups)
        #pragma unroll
        for (int u = 0; u < 4; ++u)
            #pragma unroll
            for (int kc = 0; kc < 4; ++kc)
                hi[u][kc] = *(const f16x8*)&hs[ig * 4 + u][kb + kc * 32 + ks];

        // ---- 16 MFMAs, 4 independent acc chains ----
        #pragma unroll
        for (int u = 0; u < 4; ++u)
            #pragma unroll
            for (int kc = 0; kc < 4; ++kc) {
                const f16x8 z = {};
                f16x8 s = __builtin_elementwise_max(hi[u][kc] + hj[kc], z);
                acc[u] = __builtin_amdgcn_mfma_f32_16x16x32_f16(
                    w2h[kc], s, acc[u], 0, 0, 0);
            }
    }

    // ---- store: lane<32 holds D[tb..tb+3][jr] (proven exact-WRITE pattern) ----
    if (lane < 32) {
        #pragma unroll
        for (int u = 0; u < 4; ++u) {
            const int i = i0 + ig * 4 + u;
            const int j = j0 + jr;
            float* op = out + ((size_t)(b * NLANES + i) * NLANES + j) * NUM_TYPES + tb;
            const floatx4 a = acc[u];
            if (tb == 0) {
                float v4[4] = { a[0] + bias2[0], a[1] + bias2[1],
                                a[2] + bias2[2], a[3] + bias2[3] };
                __builtin_memcpy(op, v4, 16);
            } else {
                float v2[2] = { a[0] + bias2[0], a[1] + bias2[1] };
                __builtin_memcpy(op, v2, 8);
                op[2] = a[2] + bias2[2];
            }
        }
    }
}

extern "C" void kernel_launch(void* const* d_in, const int* in_sizes, int n_in,
                              void* d_out, int out_size, void* d_ws, size_t ws_size,
                              hipStream_t stream) {
    const float* x  = (const float*)d_in[0];   // (2,512,256)
    const float* W1 = (const float*)d_in[1];   // (512,256)
    const float* b1 = (const float*)d_in[2];   // (256)
    const float* W2 = (const float*)d_in[3];   // (256,7)
    const float* b2 = (const float*)d_in[4];   // (7)
    float* out = (float*)d_out;                // (2,512,512,7) fp32

    char* ws = (char*)d_ws;
    _Float16* Hi16 = (_Float16*)ws;
    _Float16* Hj16 = (_Float16*)(ws + 512u * 1024u);
    _Float16* w2f  = (_Float16*)(ws + 1024u * 1024u);

    k1_mfma<<<dim3(32, 16), 256, 0, stream>>>(x, W1, b1, W2, Hi16, Hj16, w2f);
    // grid: (32 j-tiles, 32 i-tiles, batch) = 2048 blocks
    k2_pair<<<dim3(NLANES / 16, NLANES / 16, BATCH), 256, 0, stream>>>(
        Hi16, Hj16, w2f, b2, out);
}

// Round 19
// 19.828 us; speedup vs baseline: 6.4360x; 1.0270x over previous
//
#include <hip/hip_runtime.h>

#define D_MODEL   256
#define NUM_TYPES 7
#define BATCH     2
#define NLANES    512
#define LSTR      264   // f16 LDS row stride: 528B/row -> 2-way bank max (free, m136)

typedef _Float16  f16x8   __attribute__((ext_vector_type(8)));
typedef float     floatx4 __attribute__((ext_vector_type(4)));

// ws: Hi16 @ 0 (512 KB) = f16(x@W1a+b1); Hj16 @ 512 KB (512 KB) = f16(x@W1b);
//     w2f @ 1 MB (8 KB) = W2^T MFMA A-fragments (slot = kc*64+lane, f16x8 each).
// Measured-best configuration (round 10: 19.95 us). k1 ~2.5 us, k2 ~12 us,
// remainder = launch/drain overhead (fusion attempts all regressed).

// ---------------- Kernel 1: H16 = f16(x @ [W1a|W1b] (+b1)) via f16 MFMA ----------
__global__ __launch_bounds__(256) void k1_mfma(
    const float* __restrict__ x, const float* __restrict__ W1,
    const float* __restrict__ b1, const float* __restrict__ W2,
    _Float16* __restrict__ Hi16, _Float16* __restrict__ Hj16,
    _Float16* __restrict__ w2f)
{
    __shared__ __align__(16) _Float16 xs[64][LSTR];   // 33 KB

    const int tid  = threadIdx.x, lane = tid & 63, w = tid >> 6;
    const int nt   = blockIdx.x;                  // 0..31 ; half = nt>>4
    const int half = nt >> 4;
    const int nc   = (nt & 15) * 16;
    const int r0   = blockIdx.y * 64;             // row-tile base
    const int jr   = lane & 15, g = lane >> 4, ks = g * 8;

    // ---- stage 64 x-rows (64 KB f32 -> 32 KB f16), fully coalesced ----
    {
        const float4* xsrc = (const float4*)(x + (size_t)r0 * D_MODEL);
        #pragma unroll
        for (int q = 0; q < 8; ++q) {
            const int gg = q * 512 + tid * 2;     // float4 granule (pair start)
            const int r  = gg >> 6;               // row 0..63
            const int c4 = gg & 63;               // even
            const float4 v0 = xsrc[gg];
            const float4 v1 = xsrc[gg + 1];
            f16x8 o;
            o[0] = (_Float16)v0.x; o[1] = (_Float16)v0.y;
            o[2] = (_Float16)v0.z; o[3] = (_Float16)v0.w;
            o[4] = (_Float16)v1.x; o[5] = (_Float16)v1.y;
            o[6] = (_Float16)v1.z; o[7] = (_Float16)v1.w;
            *(f16x8*)&xs[r][c4 * 4] = o;
        }
    }

    // ---- B-frags: W1 cols nc..nc+15, strided (L2-hot); hides under staging ----
    f16x8 w1f[8];
    {
        const float* wb = W1 + (size_t)(half * D_MODEL + ks) * D_MODEL + nc + jr;
        #pragma unroll
        for (int kc = 0; kc < 8; ++kc)
            #pragma unroll
            for (int e = 0; e < 8; ++e)
                w1f[kc][e] = (_Float16)wb[(size_t)(kc * 32 + e) * D_MODEL];
    }

    __syncthreads();

    // ---- wave w: rows r0 + w*16 .. +15 ----
    floatx4 acc = {0.f, 0.f, 0.f, 0.f};
    #pragma unroll
    for (int kc = 0; kc < 8; ++kc) {
        const f16x8 a = *(const f16x8*)&xs[w * 16 + jr][kc * 32 + ks];
        acc = __builtin_amdgcn_mfma_f32_16x16x32_f16(a, w1f[kc], acc, 0, 0, 0);
    }

    _Float16* Hb = half ? Hj16 : Hi16;
    const float bias = half ? 0.f : b1[nc + jr];
    const int m0 = r0 + w * 16;
    #pragma unroll
    for (int r = 0; r < 4; ++r)
        Hb[(size_t)(m0 + g * 4 + r) * D_MODEL + nc + jr] = (_Float16)(acc[r] + bias);

    // ---- one block builds the W2^T fragment table (8 KB) ----
    if (nt == 0 && blockIdx.y == 0) {
        #pragma unroll
        for (int s0 = 0; s0 < 2; ++s0) {
            const int s   = tid + s0 * 256;       // slot 0..511
            const int l2  = s & 63, kc2 = s >> 6;
            const int t2  = l2 & 15, ks2 = (l2 >> 4) * 8;
            f16x8 frag;
            #pragma unroll
            for (int e = 0; e < 8; ++e) {
                const int k = kc2 * 32 + ks2 + e;
                frag[e] = (t2 < NUM_TYPES)
                    ? (_Float16)W2[(size_t)k * NUM_TYPES + t2] : (_Float16)0.f;
            }
            *(f16x8*)(w2f + (size_t)s * 8) = frag;
        }
    }
}

// ---------------- Kernel 2: out[b,i,j,:] = relu(Hi[i]+Hj[j]) @ W2 + b2 ----------
// r8-proven: tile 16i x 32j, 256 thr = 4 waves, grid (16,32,2) = 1024 blocks.
// Wave = 4 i's x BOTH j-groups. hA/hB ping-pong hides ds latency under MFMAs.
#define COMPUTE_U(H, U)                                                          \
    do {                                                                         \
        _Pragma("unroll")                                                        \
        for (int kc = 0; kc < 4; ++kc) {                                         \
            const f16x8 z = {};                                                  \
            f16x8 s0 = __builtin_elementwise_max(H[kc] + hjr0[kc], z);           \
            acc##U[0] = __builtin_amdgcn_mfma_f32_16x16x32_f16(                  \
                w2h[kc], s0, acc##U[0], 0, 0, 0);                                \
            f16x8 s1 = __builtin_elementwise_max(H[kc] + hjr1[kc], z);           \
            acc##U[1] = __builtin_amdgcn_mfma_f32_16x16x32_f16(                  \
                w2h[kc], s1, acc##U[1], 0, 0, 0);                                \
        }                                                                        \
    } while (0)

__global__ __launch_bounds__(256, 4) void k2_pair(
    const _Float16* __restrict__ Hi16, const _Float16* __restrict__ Hj16,
    const _Float16* __restrict__ w2f, const float* __restrict__ b2,
    float* __restrict__ out)
{
    __shared__ _Float16 hs[48][LSTR];   // rows 0..15: Hi(i0+r); 16..47: Hj(j0+r-16)

    const int tid  = threadIdx.x;       // 0..255
    const int lane = tid & 63, w = tid >> 6;
    const int b    = blockIdx.z;
    const int j0   = blockIdx.x * 32;
    const int i0   = blockIdx.y * 16;
    const int jr   = lane & 15, g = lane >> 4, ks = g * 8;

    // ---- stage 48 rows (24 KB of H), uniform Hi / Hj halves, coalesced ----
    #pragma unroll
    for (int q = 0; q < 2; ++q) {       // granules 0..511 -> Hi rows 0..15
        const int gg = tid + q * 256;
        const int r  = gg >> 5;
        const int c  = (gg & 31) * 8;
        *(f16x8*)&hs[r][c] = *(const f16x8*)(
            Hi16 + (size_t)(b * NLANES + i0 + r) * D_MODEL + c);
    }
    #pragma unroll
    for (int q = 0; q < 4; ++q) {       // granules 0..1023 -> Hj rows 16..47
        const int gg = tid + q * 256;
        const int r  = gg >> 5;
        const int c  = (gg & 31) * 8;
        *(f16x8*)&hs[16 + r][c] = *(const f16x8*)(
            Hj16 + (size_t)(b * NLANES + j0 + r) * D_MODEL + c);
    }

    const int tb = g * 4;
    float bias2[4];
    #pragma unroll
    for (int r = 0; r < 4; ++r)
        bias2[r] = (tb + r < NUM_TYPES) ? b2[tb + r] : 0.f;

    __syncthreads();

    const int ig = w;                   // wave's 4 i's: i0 + ig*4 + u
    const f16x8* w2fp = (const f16x8*)w2f + lane;   // + (kch*4+kc)*64

    floatx4 acc0[2], acc1[2], acc2[2], acc3[2];
    #pragma unroll
    for (int jg = 0; jg < 2; ++jg) {
        acc0[jg] = (floatx4){0.f, 0.f, 0.f, 0.f};
        acc1[jg] = (floatx4){0.f, 0.f, 0.f, 0.f};
        acc2[jg] = (floatx4){0.f, 0.f, 0.f, 0.f};
        acc3[jg] = (floatx4){0.f, 0.f, 0.f, 0.f};
    }

    #pragma unroll
    for (int kch = 0; kch < 2; ++kch) {
        const int kb = kch * 128;       // f16 col base of this k-half

        f16x8 w2h[4];                   // this half's A-frags: coalesced b128
        #pragma unroll
        for (int kc = 0; kc < 4; ++kc)
            w2h[kc] = w2fp[(kch * 4 + kc) * 64];

        f16x8 hjr0[4], hjr1[4];         // both j-groups, resident
        #pragma unroll
        for (int kc = 0; kc < 4; ++kc) {
            hjr0[kc] = *(const f16x8*)&hs[16 + jr][kb + kc * 32 + ks];
            hjr1[kc] = *(const f16x8*)&hs[32 + jr][kb + kc * 32 + ks];
        }

        f16x8 hA[4], hB[4];             // ping-pong i-fragments
        #pragma unroll
        for (int kc = 0; kc < 4; ++kc)
            hA[kc] = *(const f16x8*)&hs[ig * 4 + 0][kb + kc * 32 + ks];
        #pragma unroll
        for (int kc = 0; kc < 4; ++kc)
            hB[kc] = *(const f16x8*)&hs[ig * 4 + 1][kb + kc * 32 + ks];

        COMPUTE_U(hA, 0);               // u=0
        #pragma unroll
        for (int kc = 0; kc < 4; ++kc)  // refill hA for u=2 (hides under u=1)
            hA[kc] = *(const f16x8*)&hs[ig * 4 + 2][kb + kc * 32 + ks];
        COMPUTE_U(hB, 1);               // u=1
        #pragma unroll
        for (int kc = 0; kc < 4; ++kc)  // refill hB for u=3 (hides under u=2)
            hB[kc] = *(const f16x8*)&hs[ig * 4 + 3][kb + kc * 32 + ks];
        COMPUTE_U(hA, 2);               // u=2
        COMPUTE_U(hB, 3);               // u=3
    }

    // ---- store: lane<32 holds D[tb..tb+3][jr] (proven exact-WRITE pattern) ----
    if (lane < 32) {
        floatx4* accs[4] = {acc0, acc1, acc2, acc3};
        #pragma unroll
        for (int u = 0; u < 4; ++u) {
            const int i = i0 + ig * 4 + u;
            #pragma unroll
            for (int jg = 0; jg < 2; ++jg) {
                const floatx4 a = accs[u][jg];
                const int j = j0 + jg * 16 + jr;
                float* op = out + ((size_t)(b * NLANES + i) * NLANES + j) * NUM_TYPES + tb;
                if (tb == 0) {
                    float v4[4] = { a[0] + bias2[0], a[1] + bias2[1],
                                    a[2] + bias2[2], a[3] + bias2[3] };
                    __builtin_memcpy(op, v4, 16);
                } else {
                    float v2[2] = { a[0] + bias2[0], a[1] + bias2[1] };
                    __builtin_memcpy(op, v2, 8);
                    op[2] = a[2] + bias2[2];
                }
            }
        }
    }
}

extern "C" void kernel_launch(void* const* d_in, const int* in_sizes, int n_in,
                              void* d_out, int out_size, void* d_ws, size_t ws_size,
                              hipStream_t stream) {
    const float* x  = (const float*)d_in[0];   // (2,512,256)
    const float* W1 = (const float*)d_in[1];   // (512,256)
    const float* b1 = (const float*)d_in[2];   // (256)
    const float* W2 = (const float*)d_in[3];   // (256,7)
    const float* b2 = (const float*)d_in[4];   // (7)
    float* out = (float*)d_out;                // (2,512,512,7) fp32

    char* ws = (char*)d_ws;
    _Float16* Hi16 = (_Float16*)ws;
    _Float16* Hj16 = (_Float16*)(ws + 512u * 1024u);
    _Float16* w2f  = (_Float16*)(ws + 1024u * 1024u);

    k1_mfma<<<dim3(32, 16), 256, 0, stream>>>(x, W1, b1, W2, Hi16, Hj16, w2f);
    k2_pair<<<dim3(NLANES / 32, NLANES / 16, BATCH), 256, 0, stream>>>(
        Hi16, Hj16, w2f, b2, out);
}